// Round 2
// baseline (384.248 us; speedup 1.0000x reference)
//
#include <hip/hip_runtime.h>
#include <math.h>

#define NROWS   32768
#define CDIM    256
#define KCODES  1024
#define ZQ_ELEMS 8388608   // 32*256*32*32

typedef short  bshort8 __attribute__((ext_vector_type(8)));   // 8 bf16 (4 VGPRs)
typedef float  f32x4   __attribute__((ext_vector_type(4)));

// ---- ws layout (floats) ----
#define ESQ_OFF   0          // 1024
#define ZSQ_OFF   1024       // 32768
#define TB_OFF    33792      // 2*32768 best
#define TS_OFF    99328      // 2*32768 second
#define TI_OFF    164864     // 2*32768 best idx (int)
#define IDX_OFF   230400     // 32768 (int)
#define LIST_OFF  263168     // 32768 (int)
#define CNT_OFF   295936     // 1 int
#define ACC_OFF   295937     // 1 float

// ---- d_out scratch (floats, inside z_q region, overwritten by gather later) ----
#define BHI_OFF   0          // 131072 floats = 64ct*8ks*64lane*4dw
#define BLO_OFF   131072

#define MARGIN_REL 4.0e-7f

__device__ __forceinline__ ushort f2bf(float f) {
    union { float f; uint u; } v; v.f = f;
    uint lsb = (v.u >> 16) & 1u;
    return (ushort)((v.u + 0x7fffu + lsb) >> 16);
}
__device__ __forceinline__ float bf2f(ushort b) {
    union { uint u; float f; } v; v.u = ((uint)b) << 16;
    return v.f;
}

// ================= prep: e_sq (numpy pairwise semantics) =================
__global__ __launch_bounds__(256) void esq_kernel(const float* __restrict__ cb,
                                                  float* __restrict__ esq) {
    int k = blockIdx.x * 256 + threadIdx.x;
    if (k >= KCODES) return;
    const float* p = cb + (size_t)k * CDIM;
    float half_[2];
    for (int h = 0; h < 2; ++h) {
        const float* q = p + h * 128;
        float r8[8];
#pragma unroll
        for (int j = 0; j < 8; ++j) { float v = q[j]; r8[j] = __fmul_rn(v, v); }
        for (int i = 8; i < 128; i += 8) {
#pragma unroll
            for (int j = 0; j < 8; ++j) {
                float v = q[i + j];
                r8[j] = __fadd_rn(r8[j], __fmul_rn(v, v));
            }
        }
        half_[h] = __fadd_rn(__fadd_rn(__fadd_rn(r8[0], r8[1]), __fadd_rn(r8[2], r8[3])),
                             __fadd_rn(__fadd_rn(r8[4], r8[5]), __fadd_rn(r8[6], r8[7])));
    }
    esq[k] = __fadd_rn(half_[0], half_[1]);
}

// ================= prep: z_sq per row (numpy pairwise semantics) =================
__global__ __launch_bounds__(256) void zsq_kernel(const float* __restrict__ z,
                                                  float* __restrict__ zsq) {
    int row = blockIdx.x * 256 + threadIdx.x;     // 0..32767
    int b = row >> 10, hw = row & 1023;
    const float* p = z + (size_t)b * 262144 + hw; // element k at p[k*1024]
    float half_[2];
    for (int h = 0; h < 2; ++h) {
        const float* q = p + (size_t)h * 128 * 1024;
        float r8[8];
#pragma unroll
        for (int j = 0; j < 8; ++j) { float v = q[(size_t)j * 1024]; r8[j] = __fmul_rn(v, v); }
        for (int i = 8; i < 128; i += 8) {
#pragma unroll
            for (int j = 0; j < 8; ++j) {
                float v = q[(size_t)(i + j) * 1024];
                r8[j] = __fadd_rn(r8[j], __fmul_rn(v, v));
            }
        }
        half_[h] = __fadd_rn(__fadd_rn(__fadd_rn(r8[0], r8[1]), __fadd_rn(r8[2], r8[3])),
                             __fadd_rn(__fadd_rn(r8[4], r8[5]), __fadd_rn(r8[6], r8[7])));
    }
    zsq[row] = __fadd_rn(half_[0], half_[1]);
}

// ================= prep: pack codebook into MFMA B-fragments (bf16 hi/lo) =================
// layout: [ct(64)][ks(8)][lane(64)][4 dwords]; frag elem j -> cb[ct*16+(lane&15)][ks*32+(lane>>4)*8+j]
__global__ __launch_bounds__(256) void packB_kernel(const float* __restrict__ cb,
                                                    uint* __restrict__ Bhi, uint* __restrict__ Blo) {
    int F = blockIdx.x * 256 + threadIdx.x;   // 0..32767 frag id
    int ct = F >> 9, ks = (F >> 6) & 7, ln = F & 63;
    int code = ct * 16 + (ln & 15);
    int k0 = ks * 32 + (ln >> 4) * 8;
    const float* p = cb + (size_t)code * CDIM + k0;
    float v[8];
    float4 va = *(const float4*)p;
    float4 vb = *(const float4*)(p + 4);
    v[0]=va.x; v[1]=va.y; v[2]=va.z; v[3]=va.w; v[4]=vb.x; v[5]=vb.y; v[6]=vb.z; v[7]=vb.w;
    uint h[4], l[4];
#pragma unroll
    for (int d = 0; d < 4; ++d) {
        ushort h0 = f2bf(v[2*d]);   float r0 = v[2*d]   - bf2f(h0); ushort l0 = f2bf(r0);
        ushort h1 = f2bf(v[2*d+1]); float r1 = v[2*d+1] - bf2f(h1); ushort l1 = f2bf(r1);
        h[d] = (uint)h0 | ((uint)h1 << 16);
        l[d] = (uint)l0 | ((uint)l1 << 16);
    }
    *(uint4*)(Bhi + (size_t)F * 4) = make_uint4(h[0], h[1], h[2], h[3]);
    *(uint4*)(Blo + (size_t)F * 4) = make_uint4(l[0], l[1], l[2], l[3]);
}

// ================= main: MFMA distances + per-row top-2 =================
// grid 256 = 128 rowgroups x 2 code-halves; block 256 thr = 4 waves; 256 rows/block.
__global__ __launch_bounds__(256, 1) void main_mfma(const float* __restrict__ z,
                                                    const float* __restrict__ Bhi_f,
                                                    const float* __restrict__ Blo_f,
                                                    const float* __restrict__ esq,
                                                    const float* __restrict__ zsq,
                                                    float* __restrict__ tb, float* __restrict__ ts,
                                                    int* __restrict__ ti) {
    __shared__ uint a_hi[2][16][64][4];
    __shared__ uint a_lo[2][16][64][4];
    __shared__ uint b_hi[2][8][64][4];
    __shared__ uint b_lo[2][8][64][4];
    __shared__ float esq_s[512];
    __shared__ float zsq_s[256];

    const int tid  = threadIdx.x;
    const int rg   = blockIdx.x >> 1;
    const int half = blockIdx.x & 1;
    const int w    = tid >> 6;
    const int lane = tid & 63;
    const int rt_l = tid >> 4;     // A-pack role: rowtile 0..15
    const int m    = tid & 15;     // A-pack role: row-within-tile

    const uint* Bhi = (const uint*)Bhi_f;
    const uint* Blo = (const uint*)Blo_f;

    // stage per-block esq half + zsq slice
    {
        float2 e2 = *(const float2*)(esq + half * 512 + tid * 2);
        esq_s[tid * 2] = e2.x; esq_s[tid * 2 + 1] = e2.y;
        zsq_s[tid] = zsq[rg * 256 + tid];
    }

    const float* zb = z + (size_t)(rg >> 2) * 262144 + (size_t)(rg & 3) * 256;

    // per-lane top-2 state: slot s = rt*4+reg  (row = (w*4+rt)*16 + (lane>>4)*4 + reg)
    float best[16], sec[16]; int bidx[16];
#pragma unroll
    for (int s = 0; s < 16; ++s) { best[s] = INFINITY; sec[s] = INFINITY; bidx[s] = 0; }

    float v[4][8];

#define LOADA(KS)                                                                  \
    _Pragma("unroll") for (int i = 0; i < 4; ++i)                                  \
    _Pragma("unroll") for (int j = 0; j < 8; ++j)                                  \
        v[i][j] = zb[(size_t)((KS) * 32 + i * 8 + j) * 1024 + rt_l * 16 + m];

#define PACKA(BUF)                                                                 \
    _Pragma("unroll") for (int i = 0; i < 4; ++i) {                                \
        uint h[4], l[4];                                                           \
        _Pragma("unroll") for (int d = 0; d < 4; ++d) {                            \
            ushort h0 = f2bf(v[i][2*d]);   float r0 = v[i][2*d]   - bf2f(h0);      \
            ushort h1 = f2bf(v[i][2*d+1]); float r1 = v[i][2*d+1] - bf2f(h1);      \
            h[d] = (uint)h0 | ((uint)h1 << 16);                                    \
            l[d] = (uint)f2bf(r0) | ((uint)f2bf(r1) << 16);                        \
        }                                                                          \
        *(uint4*)&a_hi[BUF][rt_l][i * 16 + m][0] = make_uint4(h[0],h[1],h[2],h[3]);\
        *(uint4*)&a_lo[BUF][rt_l][i * 16 + m][0] = make_uint4(l[0],l[1],l[2],l[3]);\
    }

#define STAGEB(BUF, CTG, KS)                                                       \
    _Pragma("unroll") for (int c = 0; c < 2; ++c) {                                \
        int ctl = w * 2 + c;                                                       \
        size_t off = ((size_t)((half * 32 + (CTG) * 8 + ctl) * 8 + (KS)) * 64 + lane) * 4; \
        __builtin_amdgcn_global_load_lds(                                          \
            (const __attribute__((address_space(1))) void*)(Bhi + off),            \
            (__attribute__((address_space(3))) void*)(&b_hi[BUF][ctl][0][0]), 16, 0, 0); \
        __builtin_amdgcn_global_load_lds(                                          \
            (const __attribute__((address_space(1))) void*)(Blo + off),            \
            (__attribute__((address_space(3))) void*)(&b_lo[BUF][ctl][0][0]), 16, 0, 0); \
    }

    for (int ctg = 0; ctg < 4; ++ctg) {
        f32x4 acc[4][8];
#pragma unroll
        for (int rt = 0; rt < 4; ++rt)
#pragma unroll
            for (int c = 0; c < 8; ++c) acc[rt][c] = (f32x4){0.f, 0.f, 0.f, 0.f};

        // prologue ks=0
        LOADA(0);
        STAGEB(0, ctg, 0);
        PACKA(0);
        __syncthreads();

        for (int ks = 0; ks < 8; ++ks) {
            const int buf = ks & 1;
            if (ks < 7) { LOADA(ks + 1); STAGEB(buf ^ 1, ctg, ks + 1); }

            // compute(buf)
            {
                bshort8 bh[8], bl[8];
#pragma unroll
                for (int c = 0; c < 8; ++c) {
                    bh[c] = *(const bshort8*)&b_hi[buf][c][lane][0];
                    bl[c] = *(const bshort8*)&b_lo[buf][c][lane][0];
                }
#pragma unroll
                for (int rt = 0; rt < 4; ++rt) {
                    bshort8 ah = *(const bshort8*)&a_hi[buf][w * 4 + rt][lane][0];
                    bshort8 al = *(const bshort8*)&a_lo[buf][w * 4 + rt][lane][0];
#pragma unroll
                    for (int c = 0; c < 8; ++c) {
                        acc[rt][c] = __builtin_amdgcn_mfma_f32_16x16x32_bf16(al, bh[c], acc[rt][c], 0, 0, 0);
                        acc[rt][c] = __builtin_amdgcn_mfma_f32_16x16x32_bf16(ah, bl[c], acc[rt][c], 0, 0, 0);
                        acc[rt][c] = __builtin_amdgcn_mfma_f32_16x16x32_bf16(ah, bh[c], acc[rt][c], 0, 0, 0);
                    }
                }
            }

            if (ks < 7) PACKA(buf ^ 1);
            __syncthreads();
        }

        // epilogue: distances + top-2 update
        {
            const int g = lane >> 4, cl = lane & 15;
#pragma unroll
            for (int rt = 0; rt < 4; ++rt)
#pragma unroll
                for (int c = 0; c < 8; ++c) {
                    int col_l = (ctg * 8 + c) * 16 + cl;
                    float es = esq_s[col_l];
                    int code = half * 512 + col_l;
                    f32x4 a = acc[rt][c];
#pragma unroll
                    for (int reg = 0; reg < 4; ++reg) {
                        int rowl = (w * 4 + rt) * 16 + g * 4 + reg;
                        float t1 = __fadd_rn(zsq_s[rowl], es);
                        float dd = __fadd_rn(t1, __fmul_rn(-2.0f, a[reg]));
                        int s = rt * 4 + reg;
                        if (dd < best[s]) { sec[s] = best[s]; best[s] = dd; bidx[s] = code; }
                        else if (dd < sec[s]) sec[s] = dd;
                    }
                }
        }
    }

    // cross-lane merge over the 16 col-lanes (same row group)
#pragma unroll
    for (int mk = 1; mk <= 8; mk <<= 1) {
#pragma unroll
        for (int s = 0; s < 16; ++s) {
            float ob = __shfl_xor(best[s], mk, 64);
            float os = __shfl_xor(sec[s],  mk, 64);
            int   oi = __shfl_xor(bidx[s], mk, 64);
            float mx = fmaxf(best[s], ob);
            sec[s] = fminf(fminf(sec[s], os), mx);
            if (ob < best[s] || (ob == best[s] && oi < bidx[s])) { best[s] = ob; bidx[s] = oi; }
        }
    }
    if ((lane & 15) == 0) {
        const int g = lane >> 4;
#pragma unroll
        for (int s = 0; s < 16; ++s) {
            int rt = s >> 2, reg = s & 3;
            int row = rg * 256 + (w * 4 + rt) * 16 + g * 4 + reg;
            size_t o = (size_t)half * NROWS + row;
            tb[o] = best[s]; ts[o] = sec[s]; ti[o] = bidx[s];
        }
    }
#undef LOADA
#undef PACKA
#undef STAGEB
}

// ================= finalize: merge halves, flag near-ties =================
__global__ __launch_bounds__(256) void finalize_kernel(const float* __restrict__ tb,
                                                       const float* __restrict__ ts,
                                                       const int* __restrict__ ti,
                                                       float* __restrict__ oidxf,
                                                       int* __restrict__ idx_i,
                                                       int* __restrict__ list,
                                                       int* __restrict__ count) {
    int row = blockIdx.x * 256 + threadIdx.x;
    float b0 = tb[row], b1 = tb[NROWS + row];
    float s0 = ts[row], s1 = ts[NROWS + row];
    int   i0 = ti[row], i1 = ti[NROWS + row];
    float mx = fmaxf(b0, b1);
    float sec = fminf(fminf(s0, s1), mx);
    float best; int idx;
    if (b1 < b0) { best = b1; idx = i1; } else { best = b0; idx = i0; }
    if (sec <= best + MARGIN_REL * best) {
        int p = atomicAdd(count, 1);
        list[p] = row;
    } else {
        oidxf[row] = (float)idx;
        idx_i[row] = idx;
    }
}

// ================= rescan: exact fp32 chain for flagged rows =================
__global__ __launch_bounds__(256) void rescan_kernel(const float* __restrict__ z,
                                                     const float* __restrict__ cb,
                                                     const float* __restrict__ esq,
                                                     const float* __restrict__ zsq,
                                                     const int* __restrict__ list,
                                                     const int* __restrict__ count,
                                                     float* __restrict__ oidxf,
                                                     int* __restrict__ idx_i) {
    __shared__ float zr[8][256];
    __shared__ int   rrow[8];
    __shared__ float rb[256];
    __shared__ int   ri[256];
    int n = count[0];
    int tid = threadIdx.x;
    for (int base = blockIdx.x * 8; base < n; base += gridDim.x * 8) {
        int cnt = min(8, n - base);
        __syncthreads();
        if (tid < cnt) rrow[tid] = list[base + tid];
        __syncthreads();
        for (int r = 0; r < cnt; ++r) {
            int row = rrow[r];
            zr[r][tid] = z[((size_t)(row >> 10) * 256 + tid) * 1024 + (row & 1023)];
        }
        __syncthreads();
        float bv[8]; int bi[8];
#pragma unroll
        for (int r = 0; r < 8; ++r) { bv[r] = INFINITY; bi[r] = 0; }
        for (int cc = 0; cc < 4; ++cc) {
            int code = cc * 256 + tid;
            const float* cp = cb + (size_t)code * CDIM;
            float a[8];
#pragma unroll
            for (int r = 0; r < 8; ++r) a[r] = 0.f;
            for (int k = 0; k < 256; ++k) {
                float cv = cp[k];
#pragma unroll
                for (int r = 0; r < 8; ++r) a[r] = fmaf(zr[r][k], cv, a[r]);
            }
            float es = esq[code];
#pragma unroll
            for (int r = 0; r < 8; ++r) {
                float t1 = __fadd_rn(zsq[rrow[r]], es);
                float dd = __fadd_rn(t1, __fmul_rn(-2.0f, a[r]));
                if (dd < bv[r]) { bv[r] = dd; bi[r] = code; }
            }
        }
        for (int r = 0; r < cnt; ++r) {
            __syncthreads();
            rb[tid] = bv[r]; ri[tid] = bi[r];
            __syncthreads();
            for (int s = 128; s > 0; s >>= 1) {
                if (tid < s) {
                    if (rb[tid + s] < rb[tid] ||
                        (rb[tid + s] == rb[tid] && ri[tid + s] < ri[tid])) {
                        rb[tid] = rb[tid + s]; ri[tid] = ri[tid + s];
                    }
                }
                __syncthreads();
            }
            if (tid == 0) { int row = rrow[r]; oidxf[row] = (float)ri[0]; idx_i[row] = ri[0]; }
        }
    }
}

// ================= gather z_q + loss =================
__global__ __launch_bounds__(256) void gather_kernel(const float* __restrict__ z,
                                                     const float* __restrict__ cb,
                                                     const int* __restrict__ idx_i,
                                                     float* __restrict__ out0,
                                                     float* __restrict__ accum) {
    int tid   = threadIdx.x;
    int blk   = blockIdx.x;
    int b     = blk >> 5;
    int chunk = (blk >> 3) & 3;
    int cgrp  = blk & 7;
    int hw = chunk * 256 + tid;
    int n  = b * 1024 + hw;
    int code = idx_i[n];
    const float* cp = cb + (size_t)code * CDIM;
    float lsum = 0.0f;
    size_t base = (size_t)b * 262144 + hw;
#pragma unroll 4
    for (int c = cgrp * 32; c < cgrp * 32 + 32; ++c) {
        float zq = cp[c];
        size_t off = base + (size_t)c * 1024;
        float zv = z[off];
        out0[off] = zq;
        float dfr = zv - zq;
        lsum = fmaf(dfr, dfr, lsum);
    }
#pragma unroll
    for (int mm = 32; mm >= 1; mm >>= 1) lsum += __shfl_down(lsum, mm, 64);
    __shared__ float red[4];
    int wv = tid >> 6, ln = tid & 63;
    if (ln == 0) red[wv] = lsum;
    __syncthreads();
    if (tid == 0) atomicAdd(accum, (red[0] + red[1]) + (red[2] + red[3]));
}

__global__ void finalize_loss(const float* __restrict__ accum, float* __restrict__ out_loss) {
    out_loss[0] = accum[0] * (1.25f / 8388608.0f);
}

extern "C" void kernel_launch(void* const* d_in, const int* in_sizes, int n_in,
                              void* d_out, int out_size, void* d_ws, size_t ws_size,
                              hipStream_t stream) {
    const float* z  = (const float*)d_in[0];   // [32,256,32,32]
    const float* cb = (const float*)d_in[1];   // [1024,256]

    float* ws   = (float*)d_ws;
    float* esq  = ws + ESQ_OFF;
    float* zsq  = ws + ZSQ_OFF;
    float* tb   = ws + TB_OFF;
    float* ts   = ws + TS_OFF;
    int*   ti   = (int*)(ws + TI_OFF);
    int*   idx_i = (int*)(ws + IDX_OFF);
    int*   list = (int*)(ws + LIST_OFF);
    int*   cnt  = (int*)(ws + CNT_OFF);
    float* accum = ws + ACC_OFF;

    float* out0     = (float*)d_out;
    float* out_loss = out0 + ZQ_ELEMS;
    float* out_idxf = out0 + ZQ_ELEMS + 1;

    // big scratch inside d_out's z_q region (overwritten by gather at the end)
    float* Bhi = out0 + BHI_OFF;
    float* Blo = out0 + BLO_OFF;

    hipMemsetAsync(cnt, 0, 8, stream);  // count + accum

    esq_kernel  <<<4,    256, 0, stream>>>(cb, esq);
    zsq_kernel  <<<128,  256, 0, stream>>>(z, zsq);
    packB_kernel<<<128,  256, 0, stream>>>(cb, (uint*)Bhi, (uint*)Blo);
    main_mfma   <<<256,  256, 0, stream>>>(z, Bhi, Blo, esq, zsq, tb, ts, ti);
    finalize_kernel<<<128, 256, 0, stream>>>(tb, ts, ti, out_idxf, idx_i, list, cnt);
    rescan_kernel<<<64,  256, 0, stream>>>(z, cb, esq, zsq, list, cnt, out_idxf, idx_i);
    gather_kernel<<<1024, 256, 0, stream>>>(z, cb, idx_i, out0, accum);
    finalize_loss<<<1, 1, 0, stream>>>(accum, out_loss);
}

// Round 3
// 294.441 us; speedup vs baseline: 1.3050x; 1.3050x over previous
//
#include <hip/hip_runtime.h>
#include <math.h>

#define NROWS   32768
#define CDIM    256
#define KCODES  1024
#define ZQ_ELEMS 8388608   // 32*256*32*32

typedef short  bshort8 __attribute__((ext_vector_type(8)));   // 8 bf16 (4 VGPRs)
typedef float  f32x4   __attribute__((ext_vector_type(4)));

// ---- ws layout (floats) ----
#define ESQ_OFF   0          // 1024
#define ZSQH_OFF  1024       // 2*32768 (zsq half-sums)
#define TB_OFF    66560      // 4*32768 best
#define TS_OFF    197632     // 4*32768 second
#define TI_OFF    328704     // 4*32768 best idx (int)
#define IDX_OFF   459776     // 32768 (int)
#define LIST_OFF  492544     // 32768 (int)
#define CNT_OFF   525312     // 1 int
#define ACC_OFF   525313     // 1 float
#define BHI_OFF   525328     // 131072 uints (16B aligned)
#define BLO_OFF   656400     // 131072 uints

// ---- d_out scratch: A-fragments fill the z_q region exactly (overwritten by gather) ----
// Ahi: uint4[2048rt][8ks][64lane] = 4194304 uints ; Alo same, right after.

#define MARGIN_REL 4.0e-7f

__device__ __forceinline__ ushort f2bf(float f) {
    union { float f; uint u; } v; v.f = f;
    uint lsb = (v.u >> 16) & 1u;
    return (ushort)((v.u + 0x7fffu + lsb) >> 16);
}
__device__ __forceinline__ float bf2f(ushort b) {
    union { uint u; float f; } v; v.u = ((uint)b) << 16;
    return v.f;
}

// ================= prep: e_sq (numpy pairwise semantics) =================
__global__ __launch_bounds__(256) void esq_kernel(const float* __restrict__ cb,
                                                  float* __restrict__ esq) {
    int k = blockIdx.x * 256 + threadIdx.x;
    if (k >= KCODES) return;
    const float* p = cb + (size_t)k * CDIM;
    float half_[2];
    for (int h = 0; h < 2; ++h) {
        const float* q = p + h * 128;
        float r8[8];
#pragma unroll
        for (int j = 0; j < 8; ++j) { float v = q[j]; r8[j] = __fmul_rn(v, v); }
        for (int i = 8; i < 128; i += 8) {
#pragma unroll
            for (int j = 0; j < 8; ++j) {
                float v = q[i + j];
                r8[j] = __fadd_rn(r8[j], __fmul_rn(v, v));
            }
        }
        half_[h] = __fadd_rn(__fadd_rn(__fadd_rn(r8[0], r8[1]), __fadd_rn(r8[2], r8[3])),
                             __fadd_rn(__fadd_rn(r8[4], r8[5]), __fadd_rn(r8[6], r8[7])));
    }
    esq[k] = __fadd_rn(half_[0], half_[1]);
}

// ================= prep: pack codebook into B-fragments (bf16 hi/lo) =================
// F = (ct*8+ks)*64+lane ; elem j -> cb[ct*16+(lane&15)][ks*32+(lane>>4)*8+j]
__global__ __launch_bounds__(256) void packB_kernel(const float* __restrict__ cb,
                                                    uint* __restrict__ Bhi, uint* __restrict__ Blo) {
    int F = blockIdx.x * 256 + threadIdx.x;   // 0..32767
    int ct = F >> 9, ks = (F >> 6) & 7, ln = F & 63;
    int code = ct * 16 + (ln & 15);
    int k0 = ks * 32 + (ln >> 4) * 8;
    const float* p = cb + (size_t)code * CDIM + k0;
    float v[8];
    float4 va = *(const float4*)p;
    float4 vb = *(const float4*)(p + 4);
    v[0]=va.x; v[1]=va.y; v[2]=va.z; v[3]=va.w; v[4]=vb.x; v[5]=vb.y; v[6]=vb.z; v[7]=vb.w;
    uint h[4], l[4];
#pragma unroll
    for (int d = 0; d < 4; ++d) {
        ushort h0 = f2bf(v[2*d]);   float r0 = v[2*d]   - bf2f(h0);
        ushort h1 = f2bf(v[2*d+1]); float r1 = v[2*d+1] - bf2f(h1);
        h[d] = (uint)h0 | ((uint)h1 << 16);
        l[d] = (uint)f2bf(r0) | ((uint)f2bf(r1) << 16);
    }
    *(uint4*)(Bhi + (size_t)F * 4) = make_uint4(h[0], h[1], h[2], h[3]);
    *(uint4*)(Blo + (size_t)F * 4) = make_uint4(l[0], l[1], l[2], l[3]);
}

// ================= prep: pack z into A-fragments + zsq half-sums =================
// grid 256 = 128 rowgroups(256 rows) x 2 k-halves(128 dims). Coalesced loads via LDS transpose.
__global__ __launch_bounds__(256) void packA_kernel(const float* __restrict__ z,
                                                    uint* __restrict__ Ahi, uint* __restrict__ Alo,
                                                    float* __restrict__ zsqh) {
    __shared__ float zt[32][257];   // k-chunk x local row, padded
    const int tid = threadIdx.x;
    const int rg  = blockIdx.x >> 1;       // rowgroup: rows rg*256..+255
    const int h   = blockIdx.x & 1;        // k half
    const int b   = rg >> 2;
    const int hw0 = (rg & 3) * 256;

    float r8[8];
    const int rt0 = rg * 16;               // first global rowtile of this group

    for (int kcl = 0; kcl < 4; ++kcl) {
        const int ks = h * 4 + kcl;        // global k-step (32 dims)
        __syncthreads();
        // coalesced load: 32 dims x 256 rows
        for (int kk = 0; kk < 32; ++kk)
            zt[kk][tid] = z[((size_t)b * 256 + ks * 32 + kk) * 1024 + hw0 + tid];
        __syncthreads();

        // zsq partials (thread = row), numpy 8-accumulator order
#pragma unroll
        for (int g = 0; g < 4; ++g)
#pragma unroll
            for (int j = 0; j < 8; ++j) {
                float v = zt[g * 8 + j][tid];
                float sq = __fmul_rn(v, v);
                r8[j] = (kcl == 0 && g == 0) ? sq : __fadd_rn(r8[j], sq);
            }

        // pack 1024 frag-slots (16 rt x 64 lanes), 4 per thread
#pragma unroll
        for (int it = 0; it < 4; ++it) {
            int slot = it * 256 + tid;
            int rt_l = slot >> 6, lane = slot & 63;
            int row_l = rt_l * 16 + (lane & 15);
            int k0_l  = (lane >> 4) * 8;
            uint hh[4], ll[4];
#pragma unroll
            for (int d = 0; d < 4; ++d) {
                float v0 = zt[k0_l + 2*d][row_l];
                float v1 = zt[k0_l + 2*d + 1][row_l];
                ushort h0 = f2bf(v0); float q0 = v0 - bf2f(h0);
                ushort h1 = f2bf(v1); float q1 = v1 - bf2f(h1);
                hh[d] = (uint)h0 | ((uint)h1 << 16);
                ll[d] = (uint)f2bf(q0) | ((uint)f2bf(q1) << 16);
            }
            size_t F = ((size_t)(rt0 + rt_l) * 8 + ks) * 64 + lane;
            *(uint4*)(Ahi + F * 4) = make_uint4(hh[0], hh[1], hh[2], hh[3]);
            *(uint4*)(Alo + F * 4) = make_uint4(ll[0], ll[1], ll[2], ll[3]);
        }
    }
    float hs = __fadd_rn(__fadd_rn(__fadd_rn(r8[0], r8[1]), __fadd_rn(r8[2], r8[3])),
                         __fadd_rn(__fadd_rn(r8[4], r8[5]), __fadd_rn(r8[6], r8[7])));
    zsqh[h * NROWS + rg * 256 + tid] = hs;
}

// ================= main: frag-streaming MFMA + per-row top-2 =================
// grid 512 = 256 rowgroups(128 rows) x 2 col-halves(512 cols); 4 waves in 2x2.
__global__ __launch_bounds__(256, 2) void main_mfma(const uint* __restrict__ Ahi,
                                                    const uint* __restrict__ Alo,
                                                    const uint* __restrict__ Bhi,
                                                    const uint* __restrict__ Blo,
                                                    const float* __restrict__ esq,
                                                    const float* __restrict__ zsqh,
                                                    float* __restrict__ tb, float* __restrict__ ts,
                                                    int* __restrict__ ti) {
    __shared__ uint a_hi[2][8][64][4];
    __shared__ uint a_lo[2][8][64][4];
    __shared__ uint b_hi[2][8][64][4];
    __shared__ uint b_lo[2][8][64][4];
    __shared__ float esq_s[512];
    __shared__ float zsq_s[128];

    const int tid  = threadIdx.x;
    const int rg   = blockIdx.x >> 1;
    const int half = blockIdx.x & 1;
    const int w    = tid >> 6;
    const int lane = tid & 63;
    const int wr   = w >> 1;      // row half of block (0..1)
    const int wc   = w & 1;       // col half of wave grid (0..1)

    // static LDS: esq half + zsq rows
    {
        float2 e2 = *(const float2*)(esq + half * 512 + tid * 2);
        esq_s[tid * 2] = e2.x; esq_s[tid * 2 + 1] = e2.y;
        if (tid < 128) {
            int row = rg * 128 + tid;
            zsq_s[tid] = __fadd_rn(zsqh[row], zsqh[NROWS + row]);
        }
    }

#define GLDS(SRC, DST) __builtin_amdgcn_global_load_lds(                          \
        (const __attribute__((address_space(1))) void*)(SRC),                     \
        (__attribute__((address_space(3))) void*)(DST), 16, 0, 0)

    auto stage = [&](int t) {
        int ctg = t >> 3, ks = t & 7, buf = t & 1;
#pragma unroll
        for (int r = 0; r < 2; ++r) {
            int rtl = w * 2 + r;
            size_t FA = (((size_t)rg * 8 + rtl) * 8 + ks) * 64 + lane;
            GLDS(Ahi + FA * 4, &a_hi[buf][rtl][0][0]);
            GLDS(Alo + FA * 4, &a_lo[buf][rtl][0][0]);
            int ctl = w * 2 + r;
            size_t FB = (((size_t)half * 32 + ctg * 8 + ctl) * 8 + ks) * 64 + lane;
            GLDS(Bhi + FB * 4, &b_hi[buf][ctl][0][0]);
            GLDS(Blo + FB * 4, &b_lo[buf][ctl][0][0]);
        }
    };

    float best[16], sec[16]; int bidx[16];
#pragma unroll
    for (int s = 0; s < 16; ++s) { best[s] = INFINITY; sec[s] = INFINITY; bidx[s] = 0; }

    f32x4 acc[4][4];

    stage(0);
    __syncthreads();

    for (int t = 0; t < 32; ++t) {
        const int buf = t & 1;
        if ((t & 7) == 0) {
#pragma unroll
            for (int rt = 0; rt < 4; ++rt)
#pragma unroll
                for (int c = 0; c < 4; ++c) acc[rt][c] = (f32x4){0.f, 0.f, 0.f, 0.f};
        }
        if (t < 31) stage(t + 1);

        // compute(buf)
        {
            bshort8 bh[4], bl[4];
#pragma unroll
            for (int c = 0; c < 4; ++c) {
                bh[c] = *(const bshort8*)&b_hi[buf][wc * 4 + c][lane][0];
                bl[c] = *(const bshort8*)&b_lo[buf][wc * 4 + c][lane][0];
            }
#pragma unroll
            for (int rt = 0; rt < 4; ++rt) {
                bshort8 ah = *(const bshort8*)&a_hi[buf][wr * 4 + rt][lane][0];
                bshort8 al = *(const bshort8*)&a_lo[buf][wr * 4 + rt][lane][0];
#pragma unroll
                for (int c = 0; c < 4; ++c) {
                    acc[rt][c] = __builtin_amdgcn_mfma_f32_16x16x32_bf16(al, bh[c], acc[rt][c], 0, 0, 0);
                    acc[rt][c] = __builtin_amdgcn_mfma_f32_16x16x32_bf16(ah, bl[c], acc[rt][c], 0, 0, 0);
                    acc[rt][c] = __builtin_amdgcn_mfma_f32_16x16x32_bf16(ah, bh[c], acc[rt][c], 0, 0, 0);
                }
            }
        }

        if ((t & 7) == 7) {
            // epilogue for ctg = t>>3
            const int ctg = t >> 3;
            const int g = lane >> 4, cl = lane & 15;
#pragma unroll
            for (int rt = 0; rt < 4; ++rt)
#pragma unroll
                for (int c = 0; c < 4; ++c) {
                    int col_l = ctg * 128 + (wc * 4 + c) * 16 + cl;   // within half
                    float es = esq_s[col_l];
                    int code = half * 512 + col_l;
                    f32x4 a = acc[rt][c];
#pragma unroll
                    for (int reg = 0; reg < 4; ++reg) {
                        int rowl = wr * 64 + rt * 16 + g * 4 + reg;
                        float t1 = __fadd_rn(zsq_s[rowl], es);
                        float dd = __fadd_rn(t1, __fmul_rn(-2.0f, a[reg]));
                        int s = rt * 4 + reg;
                        if (dd < best[s]) { sec[s] = best[s]; best[s] = dd; bidx[s] = code; }
                        else if (dd < sec[s]) sec[s] = dd;
                    }
                }
        }
        __syncthreads();
    }

    // intra-wave merge over the 16 col-lanes
#pragma unroll
    for (int mk = 1; mk <= 8; mk <<= 1) {
#pragma unroll
        for (int s = 0; s < 16; ++s) {
            float ob = __shfl_xor(best[s], mk, 64);
            float os = __shfl_xor(sec[s],  mk, 64);
            int   oi = __shfl_xor(bidx[s], mk, 64);
            float mx = fmaxf(best[s], ob);
            sec[s] = fminf(fminf(sec[s], os), mx);
            if (ob < best[s] || (ob == best[s] && oi < bidx[s])) { best[s] = ob; bidx[s] = oi; }
        }
    }
    if ((lane & 15) == 0) {
        const int g = lane >> 4;
        const int q = half * 2 + wc;
#pragma unroll
        for (int s = 0; s < 16; ++s) {
            int rt = s >> 2, reg = s & 3;
            int row = rg * 128 + wr * 64 + rt * 16 + g * 4 + reg;
            size_t o = (size_t)q * NROWS + row;
            tb[o] = best[s]; ts[o] = sec[s]; ti[o] = bidx[s];
        }
    }
#undef GLDS
}

// ================= finalize: merge 4 quarters, flag near-ties =================
__global__ __launch_bounds__(256) void finalize_kernel(const float* __restrict__ tb,
                                                       const float* __restrict__ ts,
                                                       const int* __restrict__ ti,
                                                       float* __restrict__ oidxf,
                                                       int* __restrict__ idx_i,
                                                       int* __restrict__ list,
                                                       int* __restrict__ count) {
    int row = blockIdx.x * 256 + threadIdx.x;
    float b = INFINITY, s = INFINITY; int bi = 0;
#pragma unroll
    for (int q = 0; q < 4; ++q) {
        float v = tb[(size_t)q * NROWS + row];
        int  vi = ti[(size_t)q * NROWS + row];
        if (v < b || (v == b && vi < bi)) { s = b; b = v; bi = vi; }
        else s = fminf(s, v);
        s = fminf(s, ts[(size_t)q * NROWS + row]);
    }
    if (s <= b + MARGIN_REL * b) {
        int p = atomicAdd(count, 1);
        list[p] = row;
    } else {
        oidxf[row] = (float)bi;
        idx_i[row] = bi;
    }
}

// ================= rescan: exact fp32 chain for flagged rows =================
__global__ __launch_bounds__(256) void rescan_kernel(const float* __restrict__ z,
                                                     const float* __restrict__ cb,
                                                     const float* __restrict__ esq,
                                                     const float* __restrict__ zsqh,
                                                     const int* __restrict__ list,
                                                     const int* __restrict__ count,
                                                     float* __restrict__ oidxf,
                                                     int* __restrict__ idx_i) {
    __shared__ float zr[8][256];
    __shared__ int   rrow[8];
    __shared__ float rb[256];
    __shared__ int   ri[256];
    int n = count[0];
    int tid = threadIdx.x;
    for (int base = blockIdx.x * 8; base < n; base += gridDim.x * 8) {
        int cnt = min(8, n - base);
        __syncthreads();
        if (tid < cnt) rrow[tid] = list[base + tid];
        __syncthreads();
        for (int r = 0; r < cnt; ++r) {
            int row = rrow[r];
            zr[r][tid] = z[((size_t)(row >> 10) * 256 + tid) * 1024 + (row & 1023)];
        }
        __syncthreads();
        float bv[8]; int bi[8];
#pragma unroll
        for (int r = 0; r < 8; ++r) { bv[r] = INFINITY; bi[r] = 0; }
        for (int cc = 0; cc < 4; ++cc) {
            int code = cc * 256 + tid;
            const float* cp = cb + (size_t)code * CDIM;
            float a[8];
#pragma unroll
            for (int r = 0; r < 8; ++r) a[r] = 0.f;
            for (int k = 0; k < 256; ++k) {
                float cv = cp[k];
#pragma unroll
                for (int r = 0; r < 8; ++r) a[r] = fmaf(zr[r][k], cv, a[r]);
            }
            float es = esq[code];
#pragma unroll
            for (int r = 0; r < 8; ++r) {
                float zs = __fadd_rn(zsqh[rrow[r]], zsqh[NROWS + rrow[r]]);
                float t1 = __fadd_rn(zs, es);
                float dd = __fadd_rn(t1, __fmul_rn(-2.0f, a[r]));
                if (dd < bv[r]) { bv[r] = dd; bi[r] = code; }
            }
        }
        for (int r = 0; r < cnt; ++r) {
            __syncthreads();
            rb[tid] = bv[r]; ri[tid] = bi[r];
            __syncthreads();
            for (int st = 128; st > 0; st >>= 1) {
                if (tid < st) {
                    if (rb[tid + st] < rb[tid] ||
                        (rb[tid + st] == rb[tid] && ri[tid + st] < ri[tid])) {
                        rb[tid] = rb[tid + st]; ri[tid] = ri[tid + st];
                    }
                }
                __syncthreads();
            }
            if (tid == 0) { int row = rrow[r]; oidxf[row] = (float)ri[0]; idx_i[row] = ri[0]; }
        }
    }
}

// ================= gather z_q + loss =================
__global__ __launch_bounds__(256) void gather_kernel(const float* __restrict__ z,
                                                     const float* __restrict__ cb,
                                                     const int* __restrict__ idx_i,
                                                     float* __restrict__ out0,
                                                     float* __restrict__ accum) {
    int tid   = threadIdx.x;
    int blk   = blockIdx.x;
    int b     = blk >> 5;
    int chunk = (blk >> 3) & 3;
    int cgrp  = blk & 7;
    int hw = chunk * 256 + tid;
    int n  = b * 1024 + hw;
    int code = idx_i[n];
    const float* cp = cb + (size_t)code * CDIM + cgrp * 32;
    float lsum = 0.0f;
    size_t base = (size_t)b * 262144 + hw + (size_t)(cgrp * 32) * 1024;
#pragma unroll
    for (int cc = 0; cc < 8; ++cc) {
        float4 q4 = *(const float4*)(cp + cc * 4);
        float qv[4] = {q4.x, q4.y, q4.z, q4.w};
#pragma unroll
        for (int u = 0; u < 4; ++u) {
            size_t off = base + (size_t)(cc * 4 + u) * 1024;
            float zv = z[off];
            out0[off] = qv[u];
            float dfr = zv - qv[u];
            lsum = fmaf(dfr, dfr, lsum);
        }
    }
#pragma unroll
    for (int mm = 32; mm >= 1; mm >>= 1) lsum += __shfl_down(lsum, mm, 64);
    __shared__ float red[4];
    int wv = tid >> 6, ln = tid & 63;
    if (ln == 0) red[wv] = lsum;
    __syncthreads();
    if (tid == 0) atomicAdd(accum, (red[0] + red[1]) + (red[2] + red[3]));
}

__global__ void finalize_loss(const float* __restrict__ accum, float* __restrict__ out_loss) {
    out_loss[0] = accum[0] * (1.25f / 8388608.0f);
}

extern "C" void kernel_launch(void* const* d_in, const int* in_sizes, int n_in,
                              void* d_out, int out_size, void* d_ws, size_t ws_size,
                              hipStream_t stream) {
    const float* z  = (const float*)d_in[0];   // [32,256,32,32]
    const float* cb = (const float*)d_in[1];   // [1024,256]

    float* ws   = (float*)d_ws;
    float* esq  = ws + ESQ_OFF;
    float* zsqh = ws + ZSQH_OFF;
    float* tb   = ws + TB_OFF;
    float* ts   = ws + TS_OFF;
    int*   ti   = (int*)(ws + TI_OFF);
    int*   idx_i = (int*)(ws + IDX_OFF);
    int*   list = (int*)(ws + LIST_OFF);
    int*   cnt  = (int*)(ws + CNT_OFF);
    float* accum = ws + ACC_OFF;
    uint*  Bhi  = (uint*)(ws + BHI_OFF);
    uint*  Blo  = (uint*)(ws + BLO_OFF);

    float* out0     = (float*)d_out;
    float* out_loss = out0 + ZQ_ELEMS;
    float* out_idxf = out0 + ZQ_ELEMS + 1;

    // A-fragments exactly fill the z_q region of d_out (consumed before gather overwrites)
    uint* Ahi = (uint*)out0;
    uint* Alo = (uint*)(out0 + 4194304);

    hipMemsetAsync(cnt, 0, 8, stream);  // count + accum

    esq_kernel  <<<4,   256, 0, stream>>>(cb, esq);
    packB_kernel<<<128, 256, 0, stream>>>(cb, Bhi, Blo);
    packA_kernel<<<256, 256, 0, stream>>>(z, Ahi, Alo, zsqh);
    main_mfma   <<<512, 256, 0, stream>>>(Ahi, Alo, Bhi, Blo, esq, zsqh, tb, ts, ti);
    finalize_kernel<<<128, 256, 0, stream>>>(tb, ts, ti, out_idxf, idx_i, list, cnt);
    rescan_kernel<<<64, 256, 0, stream>>>(z, cb, esq, zsqh, list, cnt, out_idxf, idx_i);
    gather_kernel<<<1024, 256, 0, stream>>>(z, cb, idx_i, out0, accum);
    finalize_loss<<<1, 1, 0, stream>>>(accum, out_loss);
}